// Round 6
// baseline (4383.851 us; speedup 1.0000x reference)
//
#include <hip/hip_runtime.h>

#define T_LEN 512
#define NB    32
#define HID4  1024
#define DSTR  ((size_t)T_LEN * NB * HID4)   // per-direction xg stride (elements)

typedef short  bf16x8 __attribute__((ext_vector_type(8)));
typedef float  f32x4  __attribute__((ext_vector_type(4)));

static __device__ __forceinline__ unsigned short f2bf(float f) {
  union { float f; unsigned int i; } v; v.f = f;
  unsigned int r = v.i + 0x7FFFu + ((v.i >> 16) & 1u);
  return (unsigned short)(r >> 16);
}
static __device__ __forceinline__ unsigned short f2h(float f) {
  union { _Float16 h; unsigned short u; } v; v.h = (_Float16)f; return v.u;
}
static __device__ __forceinline__ float h2f(unsigned short u) {
  union { unsigned short u; _Float16 h; } v; v.u = u; return (float)v.h;
}
static __device__ __forceinline__ float sigm(float x) {
  return __builtin_amdgcn_rcpf(1.0f + __builtin_amdgcn_exp2f(-1.44269504f * x));
}
static __device__ __forceinline__ float tanh_fast(float x) {
  float e = __builtin_amdgcn_exp2f(2.885390082f * x);
  return 1.0f - 2.0f * __builtin_amdgcn_rcpf(e + 1.0f);
}
// convert 8 consecutive f32 -> bf16x8
static __device__ __forceinline__ bf16x8 cvt8(const float* p) {
  bf16x8 r;
  #pragma unroll
  for (int i = 0; i < 8; ++i) r[i] = (short)f2bf(p[i]);
  return r;
}

// ---------------------------------------------------------------------------
// GEMM: xg = A @ W^T + bias, written in the rec-thread-swizzled layout:
//   xg[dir][t][bh][tid(512)][c(32)]  (f16), c = nh*16 + gt*4 + r
// A: f32 [16384][K], W: f32 [1024][K]. 64x64 tile, 4 waves, K-chunks of 32.
// ---------------------------------------------------------------------------
__global__ __launch_bounds__(256) void gemm_xg(
    const float* __restrict__ A,
    const float* __restrict__ Wf,
    const float* __restrict__ Wb,
    const float* __restrict__ biasf,
    const float* __restrict__ biasb,
    unsigned short* __restrict__ out, int K)
{
  __shared__ __align__(16) unsigned short As[64][40];  // pad 32->40: benign
  __shared__ __align__(16) unsigned short Bs[64][40];

  const int dir = blockIdx.z;
  const float* W    = dir ? Wb    : Wf;
  const float* bias = dir ? biasb : biasf;
  unsigned short* outd = out + (size_t)dir * DSTR;

  const int m0 = blockIdx.x * 64;
  const int n0 = blockIdx.y * 64;
  const int tid = threadIdx.x;
  const int wv = tid >> 6, lane = tid & 63;
  const int lm = lane & 15, lq = lane >> 4;
  const int mt0 = (wv >> 1) * 32, nt0 = (wv & 1) * 32;
  const int lr = tid >> 2, ls = tid & 3;

  f32x4 acc[2][2];
  #pragma unroll
  for (int a = 0; a < 2; ++a)
    #pragma unroll
    for (int b = 0; b < 2; ++b) acc[a][b] = (f32x4){0.f, 0.f, 0.f, 0.f};

  for (int kc = 0; kc < K; kc += 32) {
    *(bf16x8*)&As[lr][ls * 8] = cvt8(A + (size_t)(m0 + lr) * K + kc + ls * 8);
    *(bf16x8*)&Bs[lr][ls * 8] = cvt8(W + (size_t)(n0 + lr) * K + kc + ls * 8);
    __syncthreads();
    bf16x8 af[2], bfr[2];
    af[0]  = *(const bf16x8*)&As[mt0 + lm][lq * 8];
    af[1]  = *(const bf16x8*)&As[mt0 + 16 + lm][lq * 8];
    bfr[0] = *(const bf16x8*)&Bs[nt0 + lm][lq * 8];
    bfr[1] = *(const bf16x8*)&Bs[nt0 + 16 + lm][lq * 8];
    #pragma unroll
    for (int mt = 0; mt < 2; ++mt)
      #pragma unroll
      for (int nt = 0; nt < 2; ++nt)
        acc[mt][nt] = __builtin_amdgcn_mfma_f32_16x16x32_bf16(af[mt], bfr[nt], acc[mt][nt], 0, 0, 0);
    __syncthreads();
  }

  #pragma unroll
  for (int nt = 0; nt < 2; ++nt) {
    const int n = n0 + nt0 + nt * 16 + lm;       // gate index 0..1023
    const float bv = bias[n];
    const int gt = n >> 8, j = n & 255;
    const int wvr = j >> 5, nh = (j >> 4) & 1, lmr = j & 15;
    #pragma unroll
    for (int mt = 0; mt < 2; ++mt)
      #pragma unroll
      for (int r4 = 0; r4 < 4; ++r4) {
        const int m = m0 + mt0 + mt * 16 + lq * 4 + r4;   // token = b*T + t
        const int b = m >> 9, t = m & 511;
        const int bh = b >> 4, lqr = (b >> 2) & 3, rr = b & 3;
        const int tidr = wvr * 64 + lqr * 16 + lmr;
        const int c = nh * 16 + gt * 4 + rr;
        outd[((((size_t)t * 2 + bh) * 512 + tidr) << 5) + c] = f2h(acc[mt][nt][r4] + bv);
      }
  }
}

// ---------------------------------------------------------------------------
// Recurrence. Grid = 4 blocks (dir*2 + batch-half), 512 threads (8 waves).
// Each wave owns hidden slice [wave*32, wave*32+32): its i,f,g,o gate rows.
// W_hh bf16 fragments: K-tiles 0..5 in registers (192), 6..7 in LDS (128 KB).
// h double-buffered in LDS in A-fragment-native layout [kt][slane][16B]
// (lane-contiguous ds_read_b128 = conflict-free; quad-skewed slane breaks
// write aliasing). Output stores deferred one step (free vmcnt drain).
// ---------------------------------------------------------------------------
__global__ __launch_bounds__(512, 2) __attribute__((amdgpu_waves_per_eu(2, 2)))
void lstm_rec(
    const unsigned short* __restrict__ xg,   // [2][T][2][512][32] f16 (swizzled)
    const float* __restrict__ whh_f,         // [1024][256] f32
    const float* __restrict__ whh_b,
    float* __restrict__ out)                 // [32][T][512] f32, col off dir*256
{
  extern __shared__ char smem[];
  unsigned short* ldsB = (unsigned short*)smem;             // 128 frags * 1 KB
  unsigned short* hbuf = (unsigned short*)(smem + 131072);  // [2][8][64][8] shorts

  const int dir = blockIdx.x >> 1, bh = blockIdx.x & 1;
  const int b0 = bh * 16;
  const float* whh = dir ? whh_b : whh_f;
  const unsigned short* xgd = xg + (size_t)dir * DSTR;
  const int wave = threadIdx.x >> 6, lane = threadIdx.x & 63;
  const int lm = lane & 15, lq = lane >> 4;
  const int j0 = wave * 32;

  // A-fragment read lane swizzle (loop-invariant): block for (quad,m) lives
  // at slane = quad*16 + ((m + 4*quad) & 15)
  const int slane = lq * 16 + ((lm + 4 * lq) & 15);

  // ---- preload W_hh fragments (B-operand: n = lane&15, k = lq*8 + j) ----
  bf16x8 breg[4][2][6];
  #pragma unroll
  for (int gt = 0; gt < 4; ++gt)
    #pragma unroll
    for (int nh = 0; nh < 2; ++nh) {
      const float* wrow = whh + (size_t)(gt * 256 + j0 + nh * 16 + lm) * 256;
      #pragma unroll
      for (int kt = 0; kt < 6; ++kt)
        breg[gt][nh][kt] = cvt8(wrow + kt * 32 + lq * 8);
      #pragma unroll
      for (int kt = 6; kt < 8; ++kt) {
        const int tl = wave * 16 + gt * 4 + nh * 2 + (kt - 6);
        *(bf16x8*)(ldsB + ((size_t)tl * 64 + lane) * 8) = cvt8(wrow + kt * 32 + lq * 8);
      }
    }

  for (int i = threadIdx.x; i < 2 * 8 * 64 * 8; i += 512) hbuf[i] = 0;
  float creg[2][4] = {{0.f, 0.f, 0.f, 0.f}, {0.f, 0.f, 0.f, 0.f}};
  float hstash[2][4];
  __syncthreads();

  for (int s = 0; s < T_LEN; ++s) {
    const int tt = dir ? (T_LEN - 1 - s) : s;
    const unsigned short* hr = hbuf + (s & 1) * 4096;
    unsigned short* hw = hbuf + ((s + 1) & 1) * 4096;

    // flush previous step's output stores (retire during this step)
    if (s > 0) {
      const int tp = dir ? (T_LEN - s) : (s - 1);
      #pragma unroll
      for (int nh = 0; nh < 2; ++nh)
        #pragma unroll
        for (int r = 0; r < 4; ++r)
          out[((size_t)(b0 + lq * 4 + r) * T_LEN + tp) * 512 + dir * 256 + j0 + nh * 16 + lm] = hstash[nh][r];
    }

    // xg half 0 (nh=0); half 1 loaded after nh=0's MFMA block
    const unsigned short* xp = xgd + ((((size_t)tt * 2 + bh) * 512 + threadIdx.x) << 5);
    bf16x8 xq[4];
    #pragma unroll
    for (int q = 0; q < 2; ++q) xq[q] = *(const bf16x8*)(xp + q * 8);

    #pragma unroll
    for (int nh = 0; nh < 2; ++nh) {
      f32x4 acc[4];
      #pragma unroll
      for (int gt = 0; gt < 4; ++gt) acc[gt] = (f32x4){0.f, 0.f, 0.f, 0.f};

      #pragma unroll
      for (int kt = 0; kt < 8; ++kt) {
        const bf16x8 afrag = *(const bf16x8*)(hr + (kt * 64 + slane) * 8);
        #pragma unroll
        for (int gt = 0; gt < 4; ++gt) {
          bf16x8 bfr;
          if (kt < 6) bfr = breg[gt][nh][kt];
          else        bfr = *(const bf16x8*)(ldsB + ((size_t)(wave * 16 + gt * 4 + nh * 2 + (kt - 6)) * 64 + lane) * 8);
          acc[gt] = __builtin_amdgcn_mfma_f32_16x16x32_bf16(afrag, bfr, acc[gt], 0, 0, 0);
        }
      }

      if (nh == 0) {  // prefetch xg half 1 behind nh=0 gate math + nh=1 MFMAs
        #pragma unroll
        for (int q = 2; q < 4; ++q) xq[q] = *(const bf16x8*)(xp + q * 8);
      }

      // h write address components for this thread's hidden index
      const int jfull = j0 + nh * 16 + lm;          // 0..255
      const int ktw   = jfull >> 5;
      const int k32   = jfull & 31;
      const int quadw = k32 >> 3;
      const int jj    = k32 & 7;
      const int wbase = ktw * 512 + quadw * 128 + jj;

      #pragma unroll
      for (int r = 0; r < 4; ++r) {
        // xg value for (nh,gt,r) lives in xq[nh*2+(gt>>1)][(gt&1)*4+r]
        const float x0 = h2f((unsigned short)xq[nh * 2 + 0][0 * 4 + r]);
        const float x1 = h2f((unsigned short)xq[nh * 2 + 0][1 * 4 + r]);
        const float x2 = h2f((unsigned short)xq[nh * 2 + 1][0 * 4 + r]);
        const float x3 = h2f((unsigned short)xq[nh * 2 + 1][1 * 4 + r]);
        const float iv = sigm(acc[0][r] + x0);
        const float fv = sigm(acc[1][r] + x1);
        const float gv = tanh_fast(acc[2][r] + x2);
        const float ov = sigm(acc[3][r] + x3);
        const float cv = fv * creg[nh][r] + iv * gv;
        creg[nh][r] = cv;
        const float hv = ov * tanh_fast(cv);
        // write into A-frag slot: slane_w = quadw*16 + ((b_row + 4*quadw)&15)
        const int srow = (lq * 4 + r + 4 * quadw) & 15;
        hw[wbase + srow * 8] = f2bf(hv);
        hstash[nh][r] = hv;
      }
    }
    __syncthreads();
  }

  // final flush (step T_LEN-1)
  {
    const int tp = dir ? 0 : (T_LEN - 1);
    #pragma unroll
    for (int nh = 0; nh < 2; ++nh)
      #pragma unroll
      for (int r = 0; r < 4; ++r)
        out[((size_t)(b0 + lq * 4 + r) * T_LEN + tp) * 512 + dir * 256 + j0 + nh * 16 + lm] = hstash[nh][r];
  }
}

// ---------------------------------------------------------------------------
extern "C" void kernel_launch(void* const* d_in, const int* in_sizes, int n_in,
                              void* d_out, int out_size, void* d_ws, size_t ws_size,
                              hipStream_t stream) {
  const float* x     = (const float*)d_in[0];
  const float* wih0f = (const float*)d_in[1];
  const float* whh0f = (const float*)d_in[2];
  const float* b0f   = (const float*)d_in[3];
  const float* wih0b = (const float*)d_in[4];
  const float* whh0b = (const float*)d_in[5];
  const float* b0b   = (const float*)d_in[6];
  const float* wih1f = (const float*)d_in[7];
  const float* whh1f = (const float*)d_in[8];
  const float* b1f   = (const float*)d_in[9];
  const float* wih1b = (const float*)d_in[10];
  const float* whh1b = (const float*)d_in[11];
  const float* b1b   = (const float*)d_in[12];
  float* out = (float*)d_out;

  // ws: xg only — [2][T][2][512][32] f16 = 64 MiB. Layer-0 hidden states are
  // routed through d_out (f32, fully overwritten by the layer-1 recurrence).
  unsigned short* xg = (unsigned short*)d_ws;

  const int REC_LDS = 131072 + 2 * 8 * 64 * 8 * 2;  // 147456 B
  hipFuncSetAttribute((const void*)lstm_rec, hipFuncAttributeMaxDynamicSharedMemorySize, REC_LDS);

  gemm_xg<<<dim3(256, 16, 2), 256, 0, stream>>>(x,   wih0f, wih0b, b0f, b0b, xg, 256);
  lstm_rec<<<4, 512, REC_LDS, stream>>>(xg, whh0f, whh0b, out);   // h1 -> d_out (f32)
  gemm_xg<<<dim3(256, 16, 2), 256, 0, stream>>>(out, wih1f, wih1b, b1f, b1b, xg, 512);
  lstm_rec<<<4, 512, REC_LDS, stream>>>(xg, whh1f, whh1b, out);
}

// Round 7
// 4168.609 us; speedup vs baseline: 1.0516x; 1.0516x over previous
//
#include <hip/hip_runtime.h>

#define T_LEN 512
#define NB    32
#define HID4  1024
#define DSTR  ((size_t)T_LEN * NB * HID4)   // per-direction xg stride (elements)

typedef short  bf16x8 __attribute__((ext_vector_type(8)));
typedef float  f32x4  __attribute__((ext_vector_type(4)));

static __device__ __forceinline__ unsigned short f2bf(float f) {
  union { float f; unsigned int i; } v; v.f = f;
  unsigned int r = v.i + 0x7FFFu + ((v.i >> 16) & 1u);
  return (unsigned short)(r >> 16);
}
static __device__ __forceinline__ unsigned short f2h(float f) {
  union { _Float16 h; unsigned short u; } v; v.h = (_Float16)f; return v.u;
}
static __device__ __forceinline__ float h2f(unsigned short u) {
  union { unsigned short u; _Float16 h; } v; v.u = u; return (float)v.h;
}
static __device__ __forceinline__ float sigm(float x) {
  return __builtin_amdgcn_rcpf(1.0f + __builtin_amdgcn_exp2f(-1.44269504f * x));
}
static __device__ __forceinline__ float tanh_fast(float x) {
  float e = __builtin_amdgcn_exp2f(2.885390082f * x);
  return 1.0f - 2.0f * __builtin_amdgcn_rcpf(e + 1.0f);
}
// convert 8 consecutive f32 -> bf16x8
static __device__ __forceinline__ bf16x8 cvt8(const float* p) {
  bf16x8 r;
  #pragma unroll
  for (int i = 0; i < 8; ++i) r[i] = (short)f2bf(p[i]);
  return r;
}

// ---------------------------------------------------------------------------
// GEMM: xg = A @ W^T + bias, written in the rec-thread-swizzled layout:
//   xg[dir][t][bh][tid(512)][c(32)]  (f16), c = nh*16 + gt*4 + r
// A: f32 [16384][K], W: f32 [1024][K]. 64x64 tile, 4 waves, K-chunks of 32.
// ---------------------------------------------------------------------------
__global__ __launch_bounds__(256) void gemm_xg(
    const float* __restrict__ A,
    const float* __restrict__ Wf,
    const float* __restrict__ Wb,
    const float* __restrict__ biasf,
    const float* __restrict__ biasb,
    unsigned short* __restrict__ out, int K)
{
  __shared__ __align__(16) unsigned short As[64][40];
  __shared__ __align__(16) unsigned short Bs[64][40];

  const int dir = blockIdx.z;
  const float* W    = dir ? Wb    : Wf;
  const float* bias = dir ? biasb : biasf;
  unsigned short* outd = out + (size_t)dir * DSTR;

  const int m0 = blockIdx.x * 64;
  const int n0 = blockIdx.y * 64;
  const int tid = threadIdx.x;
  const int wv = tid >> 6, lane = tid & 63;
  const int lm = lane & 15, lq = lane >> 4;
  const int mt0 = (wv >> 1) * 32, nt0 = (wv & 1) * 32;
  const int lr = tid >> 2, ls = tid & 3;

  f32x4 acc[2][2];
  #pragma unroll
  for (int a = 0; a < 2; ++a)
    #pragma unroll
    for (int b = 0; b < 2; ++b) acc[a][b] = (f32x4){0.f, 0.f, 0.f, 0.f};

  for (int kc = 0; kc < K; kc += 32) {
    *(bf16x8*)&As[lr][ls * 8] = cvt8(A + (size_t)(m0 + lr) * K + kc + ls * 8);
    *(bf16x8*)&Bs[lr][ls * 8] = cvt8(W + (size_t)(n0 + lr) * K + kc + ls * 8);
    __syncthreads();
    bf16x8 af[2], bfr[2];
    af[0]  = *(const bf16x8*)&As[mt0 + lm][lq * 8];
    af[1]  = *(const bf16x8*)&As[mt0 + 16 + lm][lq * 8];
    bfr[0] = *(const bf16x8*)&Bs[nt0 + lm][lq * 8];
    bfr[1] = *(const bf16x8*)&Bs[nt0 + 16 + lm][lq * 8];
    #pragma unroll
    for (int mt = 0; mt < 2; ++mt)
      #pragma unroll
      for (int nt = 0; nt < 2; ++nt)
        acc[mt][nt] = __builtin_amdgcn_mfma_f32_16x16x32_bf16(af[mt], bfr[nt], acc[mt][nt], 0, 0, 0);
    __syncthreads();
  }

  #pragma unroll
  for (int nt = 0; nt < 2; ++nt) {
    const int n = n0 + nt0 + nt * 16 + lm;       // gate index 0..1023
    const float bv = bias[n];
    const int gt = n >> 8, j = n & 255;
    const int wvr = j >> 5, nh = (j >> 4) & 1, lmr = j & 15;
    #pragma unroll
    for (int mt = 0; mt < 2; ++mt)
      #pragma unroll
      for (int r4 = 0; r4 < 4; ++r4) {
        const int m = m0 + mt0 + mt * 16 + lq * 4 + r4;   // token = b*T + t
        const int b = m >> 9, t = m & 511;
        const int bh = b >> 4, lqr = (b >> 2) & 3, rr = b & 3;
        const int tidr = wvr * 64 + lqr * 16 + lmr;
        const int c = nh * 16 + gt * 4 + rr;
        outd[((((size_t)t * 2 + bh) * 512 + tidr) << 5) + c] = f2h(acc[mt][nt][r4] + bv);
      }
  }
}

// ---------------------------------------------------------------------------
// Recurrence. Grid = 4 blocks (dir*2 + batch-half), 512 threads (8 waves).
// Each wave owns hidden slice [wave*32, wave*32+32): its i,f,g,o gate rows.
// STATIC LDS (144 KB) so the compiler sees 1 block/CU -> 2 waves/SIMD ->
// 256-VGPR cap, letting the 192 weight regs stay resident (no spill).
// h double-buffered in LDS in A-frag-native layout [kt][quad][m][j]:
// afrag read addr = kt*512 + lane*8 -> lane-contiguous ds_read_b128, clean.
// ---------------------------------------------------------------------------
__global__ __launch_bounds__(512, 2) __attribute__((amdgpu_waves_per_eu(2, 2)))
void lstm_rec(
    const unsigned short* __restrict__ xg,   // [2][T][2][512][32] f16 (swizzled)
    const float* __restrict__ whh_f,         // [1024][256] f32
    const float* __restrict__ whh_b,
    float* __restrict__ out)                 // [32][T][512] f32, col off dir*256
{
  __shared__ __align__(16) unsigned short ldsB[65536];  // 128 frags * 1 KB
  __shared__ __align__(16) unsigned short hbuf[8192];   // [2][8][4][16][8]

  const int dir = blockIdx.x >> 1, bh = blockIdx.x & 1;
  const int b0 = bh * 16;
  const float* whh = dir ? whh_b : whh_f;
  const unsigned short* xgd = xg + (size_t)dir * DSTR;
  const int wave = threadIdx.x >> 6, lane = threadIdx.x & 63;
  const int lm = lane & 15, lq = lane >> 4;
  const int j0 = wave * 32;

  // ---- preload W_hh fragments (B-operand: n = lane&15, k = lq*8 + j) ----
  bf16x8 breg[4][2][6];
  #pragma unroll
  for (int gt = 0; gt < 4; ++gt)
    #pragma unroll
    for (int nh = 0; nh < 2; ++nh) {
      const float* wrow = whh + (size_t)(gt * 256 + j0 + nh * 16 + lm) * 256;
      #pragma unroll
      for (int kt = 0; kt < 6; ++kt)
        breg[gt][nh][kt] = cvt8(wrow + kt * 32 + lq * 8);
      #pragma unroll
      for (int kt = 6; kt < 8; ++kt) {
        const int tl = wave * 16 + gt * 4 + nh * 2 + (kt - 6);
        *(bf16x8*)(ldsB + ((size_t)tl * 64 + lane) * 8) = cvt8(wrow + kt * 32 + lq * 8);
      }
    }

  for (int i = threadIdx.x; i < 8192; i += 512) hbuf[i] = 0;
  float creg[2][4] = {{0.f, 0.f, 0.f, 0.f}, {0.f, 0.f, 0.f, 0.f}};
  float hstash[2][4];
  __syncthreads();

  for (int s = 0; s < T_LEN; ++s) {
    const int tt = dir ? (T_LEN - 1 - s) : s;
    const unsigned short* hr = hbuf + (s & 1) * 4096;
    unsigned short* hw = hbuf + ((s + 1) & 1) * 4096;

    // flush previous step's output stores (retire during this step)
    if (s > 0) {
      const int tp = dir ? (T_LEN - s) : (s - 1);
      #pragma unroll
      for (int nh = 0; nh < 2; ++nh)
        #pragma unroll
        for (int r = 0; r < 4; ++r)
          out[((size_t)(b0 + lq * 4 + r) * T_LEN + tp) * 512 + dir * 256 + j0 + nh * 16 + lm] = hstash[nh][r];
    }

    // xg half 0 (nh=0); half 1 loaded after nh=0's MFMA block
    const unsigned short* xp = xgd + ((((size_t)tt * 2 + bh) * 512 + threadIdx.x) << 5);
    bf16x8 xq[4];
    #pragma unroll
    for (int q = 0; q < 2; ++q) xq[q] = *(const bf16x8*)(xp + q * 8);

    #pragma unroll
    for (int nh = 0; nh < 2; ++nh) {
      f32x4 acc[4];
      #pragma unroll
      for (int gt = 0; gt < 4; ++gt) acc[gt] = (f32x4){0.f, 0.f, 0.f, 0.f};

      #pragma unroll
      for (int kt = 0; kt < 8; ++kt) {
        const bf16x8 afrag = *(const bf16x8*)(hr + kt * 512 + lane * 8);
        #pragma unroll
        for (int gt = 0; gt < 4; ++gt) {
          bf16x8 bfr;
          if (kt < 6) bfr = breg[gt][nh][kt];
          else        bfr = *(const bf16x8*)(ldsB + ((size_t)(wave * 16 + gt * 4 + nh * 2 + (kt - 6)) * 64 + lane) * 8);
          acc[gt] = __builtin_amdgcn_mfma_f32_16x16x32_bf16(afrag, bfr, acc[gt], 0, 0, 0);
        }
      }

      if (nh == 0) {  // prefetch xg half 1 behind nh=0 gate math + nh=1 MFMAs
        #pragma unroll
        for (int q = 2; q < 4; ++q) xq[q] = *(const bf16x8*)(xp + q * 8);
      }

      // h write: A-frag-native slot for (m = lq*4+r, col jfull):
      //   kt = wave, quad = nh*2 + (lm>>3), j = lm&7
      const int wbase = wave * 512 + (nh * 2 + (lm >> 3)) * 128 + lq * 32 + (lm & 7);

      #pragma unroll
      for (int r = 0; r < 4; ++r) {
        // xg value for (nh,gt,r) lives in xq[nh*2+(gt>>1)][(gt&1)*4+r]
        const float x0 = h2f((unsigned short)xq[nh * 2 + 0][0 * 4 + r]);
        const float x1 = h2f((unsigned short)xq[nh * 2 + 0][1 * 4 + r]);
        const float x2 = h2f((unsigned short)xq[nh * 2 + 1][0 * 4 + r]);
        const float x3 = h2f((unsigned short)xq[nh * 2 + 1][1 * 4 + r]);
        const float iv = sigm(acc[0][r] + x0);
        const float fv = sigm(acc[1][r] + x1);
        const float gv = tanh_fast(acc[2][r] + x2);
        const float ov = sigm(acc[3][r] + x3);
        const float cv = fv * creg[nh][r] + iv * gv;
        creg[nh][r] = cv;
        const float hv = ov * tanh_fast(cv);
        hw[wbase + r * 8] = f2bf(hv);
        hstash[nh][r] = hv;
      }
    }
    __syncthreads();
  }

  // final flush (step T_LEN-1)
  {
    const int tp = dir ? 0 : (T_LEN - 1);
    #pragma unroll
    for (int nh = 0; nh < 2; ++nh)
      #pragma unroll
      for (int r = 0; r < 4; ++r)
        out[((size_t)(b0 + lq * 4 + r) * T_LEN + tp) * 512 + dir * 256 + j0 + nh * 16 + lm] = hstash[nh][r];
  }
}

// ---------------------------------------------------------------------------
extern "C" void kernel_launch(void* const* d_in, const int* in_sizes, int n_in,
                              void* d_out, int out_size, void* d_ws, size_t ws_size,
                              hipStream_t stream) {
  const float* x     = (const float*)d_in[0];
  const float* wih0f = (const float*)d_in[1];
  const float* whh0f = (const float*)d_in[2];
  const float* b0f   = (const float*)d_in[3];
  const float* wih0b = (const float*)d_in[4];
  const float* whh0b = (const float*)d_in[5];
  const float* b0b   = (const float*)d_in[6];
  const float* wih1f = (const float*)d_in[7];
  const float* whh1f = (const float*)d_in[8];
  const float* b1f   = (const float*)d_in[9];
  const float* wih1b = (const float*)d_in[10];
  const float* whh1b = (const float*)d_in[11];
  const float* b1b   = (const float*)d_in[12];
  float* out = (float*)d_out;

  // ws: xg only — [2][T][2][512][32] f16 = 64 MiB. Layer-0 hidden states are
  // routed through d_out (f32, fully overwritten by the layer-1 recurrence).
  unsigned short* xg = (unsigned short*)d_ws;

  gemm_xg<<<dim3(256, 16, 2), 256, 0, stream>>>(x,   wih0f, wih0b, b0f, b0b, xg, 256);
  lstm_rec<<<4, 512, 0, stream>>>(xg, whh0f, whh0b, out);   // h1 -> d_out (f32)
  gemm_xg<<<dim3(256, 16, 2), 256, 0, stream>>>(out, wih1f, wih1b, b1f, b1b, xg, 512);
  lstm_rec<<<4, 512, 0, stream>>>(xg, whh1f, whh1b, out);
}

// Round 8
// 3174.681 us; speedup vs baseline: 1.3809x; 1.3131x over previous
//
#include <hip/hip_runtime.h>

#define T_LEN 512
#define NB    32
#define HID4  1024
#define DSTR  ((size_t)T_LEN * NB * HID4)   // per-direction xg stride (elements)

typedef short  bf16x8 __attribute__((ext_vector_type(8)));
typedef float  f32x4  __attribute__((ext_vector_type(4)));

static __device__ __forceinline__ unsigned short f2bf(float f) {
  union { float f; unsigned int i; } v; v.f = f;
  unsigned int r = v.i + 0x7FFFu + ((v.i >> 16) & 1u);
  return (unsigned short)(r >> 16);
}
static __device__ __forceinline__ unsigned short f2h(float f) {
  union { _Float16 h; unsigned short u; } v; v.h = (_Float16)f; return v.u;
}
static __device__ __forceinline__ float h2f(unsigned short u) {
  union { unsigned short u; _Float16 h; } v; v.u = u; return (float)v.h;
}
static __device__ __forceinline__ float sigm(float x) {
  return __builtin_amdgcn_rcpf(1.0f + __builtin_amdgcn_exp2f(-1.44269504f * x));
}
static __device__ __forceinline__ float tanh_fast(float x) {
  float e = __builtin_amdgcn_exp2f(2.885390082f * x);
  return 1.0f - 2.0f * __builtin_amdgcn_rcpf(e + 1.0f);
}
// convert 8 consecutive f32 -> bf16x8
static __device__ __forceinline__ bf16x8 cvt8(const float* p) {
  bf16x8 r;
  #pragma unroll
  for (int i = 0; i < 8; ++i) r[i] = (short)f2bf(p[i]);
  return r;
}

// ---------------------------------------------------------------------------
// GEMM: xg = A @ W^T + bias, written in the rec-thread-swizzled layout:
//   xg[dir][t][bh][tid(512)][c(32)]  (f16), c = nh*16 + gt*4 + r
// A: f32 [16384][K], W: f32 [1024][K]. 64x64 tile, 4 waves, K-chunks of 32.
// ---------------------------------------------------------------------------
__global__ __launch_bounds__(256) void gemm_xg(
    const float* __restrict__ A,
    const float* __restrict__ Wf,
    const float* __restrict__ Wb,
    const float* __restrict__ biasf,
    const float* __restrict__ biasb,
    unsigned short* __restrict__ out, int K)
{
  __shared__ __align__(16) unsigned short As[64][40];
  __shared__ __align__(16) unsigned short Bs[64][40];

  const int dir = blockIdx.z;
  const float* W    = dir ? Wb    : Wf;
  const float* bias = dir ? biasb : biasf;
  unsigned short* outd = out + (size_t)dir * DSTR;

  const int m0 = blockIdx.x * 64;
  const int n0 = blockIdx.y * 64;
  const int tid = threadIdx.x;
  const int wv = tid >> 6, lane = tid & 63;
  const int lm = lane & 15, lq = lane >> 4;
  const int mt0 = (wv >> 1) * 32, nt0 = (wv & 1) * 32;
  const int lr = tid >> 2, ls = tid & 3;

  f32x4 acc[2][2];
  #pragma unroll
  for (int a = 0; a < 2; ++a)
    #pragma unroll
    for (int b = 0; b < 2; ++b) acc[a][b] = (f32x4){0.f, 0.f, 0.f, 0.f};

  for (int kc = 0; kc < K; kc += 32) {
    *(bf16x8*)&As[lr][ls * 8] = cvt8(A + (size_t)(m0 + lr) * K + kc + ls * 8);
    *(bf16x8*)&Bs[lr][ls * 8] = cvt8(W + (size_t)(n0 + lr) * K + kc + ls * 8);
    __syncthreads();
    bf16x8 af[2], bfr[2];
    af[0]  = *(const bf16x8*)&As[mt0 + lm][lq * 8];
    af[1]  = *(const bf16x8*)&As[mt0 + 16 + lm][lq * 8];
    bfr[0] = *(const bf16x8*)&Bs[nt0 + lm][lq * 8];
    bfr[1] = *(const bf16x8*)&Bs[nt0 + 16 + lm][lq * 8];
    #pragma unroll
    for (int mt = 0; mt < 2; ++mt)
      #pragma unroll
      for (int nt = 0; nt < 2; ++nt)
        acc[mt][nt] = __builtin_amdgcn_mfma_f32_16x16x32_bf16(af[mt], bfr[nt], acc[mt][nt], 0, 0, 0);
    __syncthreads();
  }

  #pragma unroll
  for (int nt = 0; nt < 2; ++nt) {
    const int n = n0 + nt0 + nt * 16 + lm;       // gate index 0..1023
    const float bv = bias[n];
    const int gt = n >> 8, j = n & 255;
    const int wvr = j >> 5, nh = (j >> 4) & 1, lmr = j & 15;
    #pragma unroll
    for (int mt = 0; mt < 2; ++mt)
      #pragma unroll
      for (int r4 = 0; r4 < 4; ++r4) {
        const int m = m0 + mt0 + mt * 16 + lq * 4 + r4;   // token = b*T + t
        const int b = m >> 9, t = m & 511;
        const int bh = b >> 4, lqr = (b >> 2) & 3, rr = b & 3;
        const int tidr = wvr * 64 + lqr * 16 + lmr;
        const int c = nh * 16 + gt * 4 + rr;
        outd[((((size_t)t * 2 + bh) * 512 + tidr) << 5) + c] = f2h(acc[mt][nt][r4] + bv);
      }
  }
}

// ---------------------------------------------------------------------------
// Recurrence. Grid = 4 blocks (dir*2 + batch-half), 512 threads (8 waves).
// Each wave owns hidden slice [wave*32, wave*32+32): its i,f,g,o gate rows.
// STATIC LDS (144 KB): compiler sees 1 block/CU. __launch_bounds__(512) with
// NO min-waves arg so amdgpu_waves_per_eu(2,2)'s max=2 survives -> 256-VGPR
// budget -> the 192 weight regs (kt 0..5) can stay resident. kt 6,7 in LDS.
// h double-buffered in LDS, A-frag-native layout [kt][quad][m][j]:
// read addr = kt*512 + lane*8 -> lane-contiguous ds_read_b128, conflict-free.
// Stores inline at step end (no deferred-store vmcnt FIFO pollution).
// ---------------------------------------------------------------------------
__global__ __launch_bounds__(512) __attribute__((amdgpu_waves_per_eu(2, 2)))
void lstm_rec(
    const unsigned short* __restrict__ xg,   // [2][T][2][512][32] f16 (swizzled)
    const float* __restrict__ whh_f,         // [1024][256] f32
    const float* __restrict__ whh_b,
    float* __restrict__ out)                 // [32][T][512] f32, col off dir*256
{
  __shared__ __align__(16) unsigned short ldsB[65536];  // 128 frags * 1 KB
  __shared__ __align__(16) unsigned short hbuf[8192];   // [2][8][4][16][8]

  const int dir = blockIdx.x >> 1, bh = blockIdx.x & 1;
  const int b0 = bh * 16;
  const float* whh = dir ? whh_b : whh_f;
  const unsigned short* xgd = xg + (size_t)dir * DSTR;
  const int wave = threadIdx.x >> 6, lane = threadIdx.x & 63;
  const int lm = lane & 15, lq = lane >> 4;
  const int j0 = wave * 32;

  // ---- preload W_hh fragments (B-operand: n = lane&15, k = lq*8 + j) ----
  bf16x8 breg[4][2][6];
  #pragma unroll
  for (int gt = 0; gt < 4; ++gt)
    #pragma unroll
    for (int nh = 0; nh < 2; ++nh) {
      const float* wrow = whh + (size_t)(gt * 256 + j0 + nh * 16 + lm) * 256;
      #pragma unroll
      for (int kt = 0; kt < 6; ++kt)
        breg[gt][nh][kt] = cvt8(wrow + kt * 32 + lq * 8);
      #pragma unroll
      for (int kt = 6; kt < 8; ++kt) {
        const int tl = wave * 16 + gt * 4 + nh * 2 + (kt - 6);
        *(bf16x8*)(ldsB + ((size_t)tl * 64 + lane) * 8) = cvt8(wrow + kt * 32 + lq * 8);
      }
    }

  for (int i = threadIdx.x; i < 8192; i += 512) hbuf[i] = 0;
  float creg[2][4] = {{0.f, 0.f, 0.f, 0.f}, {0.f, 0.f, 0.f, 0.f}};

  // hoisted output base: element (r, tt, nh) at obase[r*T_LEN*512 + tt*512 + nh*16]
  float* obase = out + (size_t)(b0 + lq * 4) * T_LEN * 512 + dir * 256 + j0 + lm;

  __syncthreads();

  for (int s = 0; s < T_LEN; ++s) {
    const int tt = dir ? (T_LEN - 1 - s) : s;
    const unsigned short* hr = hbuf + (s & 1) * 4096;
    unsigned short* hw = hbuf + ((s + 1) & 1) * 4096;
    const size_t tto = (size_t)tt * 512;

    // xg half 0 (nh=0); half 1 loaded after nh=0's MFMA block
    const unsigned short* xp = xgd + ((((size_t)tt * 2 + bh) * 512 + threadIdx.x) << 5);
    bf16x8 xq[4];
    #pragma unroll
    for (int q = 0; q < 2; ++q) xq[q] = *(const bf16x8*)(xp + q * 8);

    #pragma unroll
    for (int nh = 0; nh < 2; ++nh) {
      f32x4 acc[4];
      #pragma unroll
      for (int gt = 0; gt < 4; ++gt) acc[gt] = (f32x4){0.f, 0.f, 0.f, 0.f};

      #pragma unroll
      for (int kt = 0; kt < 8; ++kt) {
        const bf16x8 afrag = *(const bf16x8*)(hr + kt * 512 + lane * 8);
        #pragma unroll
        for (int gt = 0; gt < 4; ++gt) {
          bf16x8 bfr;
          if (kt < 6) bfr = breg[gt][nh][kt];
          else        bfr = *(const bf16x8*)(ldsB + ((size_t)(wave * 16 + gt * 4 + nh * 2 + (kt - 6)) * 64 + lane) * 8);
          acc[gt] = __builtin_amdgcn_mfma_f32_16x16x32_bf16(afrag, bfr, acc[gt], 0, 0, 0);
        }
      }

      if (nh == 0) {  // prefetch xg half 1 behind nh=0 gate math + nh=1 MFMAs
        #pragma unroll
        for (int q = 2; q < 4; ++q) xq[q] = *(const bf16x8*)(xp + q * 8);
      }

      // h write: A-frag-native slot for (m = lq*4+r, col jfull):
      //   kt = wave, quad = nh*2 + (lm>>3), j = lm&7
      const int wbase = wave * 512 + (nh * 2 + (lm >> 3)) * 128 + lq * 32 + (lm & 7);

      #pragma unroll
      for (int r = 0; r < 4; ++r) {
        // xg value for (nh,gt,r) lives in xq[nh*2+(gt>>1)][(gt&1)*4+r]
        const float x0 = h2f((unsigned short)xq[nh * 2 + 0][0 * 4 + r]);
        const float x1 = h2f((unsigned short)xq[nh * 2 + 0][1 * 4 + r]);
        const float x2 = h2f((unsigned short)xq[nh * 2 + 1][0 * 4 + r]);
        const float x3 = h2f((unsigned short)xq[nh * 2 + 1][1 * 4 + r]);
        const float iv = sigm(acc[0][r] + x0);
        const float fv = sigm(acc[1][r] + x1);
        const float gv = tanh_fast(acc[2][r] + x2);
        const float ov = sigm(acc[3][r] + x3);
        const float cv = fv * creg[nh][r] + iv * gv;
        creg[nh][r] = cv;
        const float hv = ov * tanh_fast(cv);
        hw[wbase + r * 8] = f2bf(hv);
        obase[(size_t)r * T_LEN * 512 + tto + nh * 16] = hv;
      }
    }
    __syncthreads();
  }
}

// ---------------------------------------------------------------------------
extern "C" void kernel_launch(void* const* d_in, const int* in_sizes, int n_in,
                              void* d_out, int out_size, void* d_ws, size_t ws_size,
                              hipStream_t stream) {
  const float* x     = (const float*)d_in[0];
  const float* wih0f = (const float*)d_in[1];
  const float* whh0f = (const float*)d_in[2];
  const float* b0f   = (const float*)d_in[3];
  const float* wih0b = (const float*)d_in[4];
  const float* whh0b = (const float*)d_in[5];
  const float* b0b   = (const float*)d_in[6];
  const float* wih1f = (const float*)d_in[7];
  const float* whh1f = (const float*)d_in[8];
  const float* b1f   = (const float*)d_in[9];
  const float* wih1b = (const float*)d_in[10];
  const float* whh1b = (const float*)d_in[11];
  const float* b1b   = (const float*)d_in[12];
  float* out = (float*)d_out;

  // ws: xg only — [2][T][2][512][32] f16 = 64 MiB. Layer-0 hidden states are
  // routed through d_out (f32, fully overwritten by the layer-1 recurrence).
  unsigned short* xg = (unsigned short*)d_ws;

  gemm_xg<<<dim3(256, 16, 2), 256, 0, stream>>>(x,   wih0f, wih0b, b0f, b0b, xg, 256);
  lstm_rec<<<4, 512, 0, stream>>>(xg, whh0f, whh0b, out);   // h1 -> d_out (f32)
  gemm_xg<<<dim3(256, 16, 2), 256, 0, stream>>>(out, wih1f, wih1b, b1f, b1b, xg, 512);
  lstm_rec<<<4, 512, 0, stream>>>(xg, whh1f, whh1b, out);
}